// Round 1
// baseline (224.460 us; speedup 1.0000x reference)
//
#include <hip/hip_runtime.h>
#include <hip/hip_bf16.h>
#include <stdint.h>

#define NPIX 4096

typedef __attribute__((ext_vector_type(8))) short bf16x8;
typedef __attribute__((ext_vector_type(16))) float f32x16;
typedef __attribute__((ext_vector_type(4))) unsigned int uint4v;

__device__ __forceinline__ unsigned short bfb(float f) {
  __hip_bfloat16 h = __float2bfloat16(f);
  return __builtin_bit_cast(unsigned short, h);
}
__device__ __forceinline__ unsigned pack2(float a, float b) {
  return (unsigned)bfb(a) | ((unsigned)bfb(b) << 16);
}
__device__ __forceinline__ f32x16 mfma32(bf16x8 a, bf16x8 b, f32x16 c) {
  return __builtin_amdgcn_mfma_f32_32x32x16_bf16(a, b, c, 0, 0, 0);
}

// ---------------- kernel 0: convert weights to bf16 ----------------
__global__ void k_cvt(const float* __restrict__ Wq, const float* __restrict__ Wk,
                      const float* __restrict__ Wv, const float* __restrict__ Wr,
                      unsigned short* __restrict__ wqk, unsigned short* __restrict__ wv,
                      unsigned short* __restrict__ wr) {
  int i = blockIdx.x * 256 + threadIdx.x;  // 0..65535
  wqk[i] = bfb(i < 32768 ? Wq[i] : Wk[i - 32768]);
  wv[i]  = bfb(Wv[i]);
  wr[i]  = bfb(Wr[i]);
}

// ---------------- kernel 1: qkv projections ----------------
// out: qT [B][N][128] bf16, kT [B][N][128] bf16, v [B][256][N] bf16
__launch_bounds__(256, 2)
__global__ void k_qkv(const float* __restrict__ x,
                      const unsigned short* __restrict__ wqk,
                      const unsigned short* __restrict__ wv,
                      const float* __restrict__ bq, const float* __restrict__ bk,
                      const float* __restrict__ bv,
                      unsigned short* __restrict__ qT, unsigned short* __restrict__ kT,
                      unsigned short* __restrict__ vV) {
  __shared__ __align__(16) unsigned short xT[64 * 256];  // [n][c] bf16, swizzled rows of 512B
  const int b = blockIdx.x & 7;
  const int n0 = (blockIdx.x >> 3) * 64;
  const int t = threadIdx.x;
  const float* xb = x + (size_t)b * 256 * NPIX;
  // stage x tile [256 c][64 n] -> LDS transposed [n][c] bf16
  #pragma unroll
  for (int p = 0; p < 16; ++p) {
    int c = (t >> 4) + p * 16;
    int nq = (t & 15) * 4;
    float4 f = *reinterpret_cast<const float4*>(xb + (size_t)c * NPIX + n0 + nq);
    float vals[4] = {f.x, f.y, f.z, f.w};
    #pragma unroll
    for (int j = 0; j < 4; ++j) {
      int n = nq + j;
      int byteoff = n * 512 + ((c * 2) ^ ((n & 7) << 4));
      xT[byteoff >> 1] = bfb(vals[j]);
    }
  }
  __syncthreads();
  const int lane = t & 63, w = t >> 6, l31 = lane & 31, hi = lane >> 5;
  f32x16 aq[2][2], av[2][2];
  #pragma unroll
  for (int a0 = 0; a0 < 2; ++a0)
    #pragma unroll
    for (int a1 = 0; a1 < 2; ++a1)
      #pragma unroll
      for (int i = 0; i < 16; ++i) { aq[a0][a1][i] = 0.f; av[a0][a1][i] = 0.f; }
  #pragma unroll
  for (int s = 0; s < 16; ++s) {  // K = 256 = 16 steps of 16
    bf16x8 xa[2];
    #pragma unroll
    for (int nt = 0; nt < 2; ++nt) {
      int n = nt * 32 + l31;
      int byteoff = n * 512 + (((s * 32 + hi * 16)) ^ ((n & 7) << 4));
      xa[nt] = *reinterpret_cast<const bf16x8*>(reinterpret_cast<const char*>(xT) + byteoff);
    }
    #pragma unroll
    for (int oc2 = 0; oc2 < 2; ++oc2) {
      int oc = w * 64 + oc2 * 32 + l31;
      bf16x8 wq = *reinterpret_cast<const bf16x8*>(wqk + oc * 256 + s * 16 + hi * 8);
      bf16x8 wvf = *reinterpret_cast<const bf16x8*>(wv + oc * 256 + s * 16 + hi * 8);
      #pragma unroll
      for (int nt = 0; nt < 2; ++nt) {
        // D[n, oc] : A = x^T (rows n), B = W^T (cols oc)
        aq[oc2][nt] = mfma32(xa[nt], wq, aq[oc2][nt]);
        // D[vc, n] : A = Wv (rows vc), B = x (cols n)
        av[oc2][nt] = mfma32(wvf, xa[nt], av[oc2][nt]);
      }
    }
  }
  // epilogue q/k: col oc = lane, rows n
  #pragma unroll
  for (int oc2 = 0; oc2 < 2; ++oc2) {
    int oc = w * 64 + oc2 * 32 + l31;
    float bias = (oc < 128) ? bq[oc] : bk[oc - 128];
    unsigned short* dst = (oc < 128) ? (qT + (size_t)b * NPIX * 128 + oc)
                                     : (kT + (size_t)b * NPIX * 128 + (oc - 128));
    #pragma unroll
    for (int nt = 0; nt < 2; ++nt)
      #pragma unroll
      for (int r = 0; r < 16; ++r) {
        int n = n0 + nt * 32 + (r & 3) + 8 * (r >> 2) + 4 * hi;
        dst[(size_t)n * 128] = bfb(aq[oc2][nt][r] + bias);
      }
  }
  // epilogue v: rows vc, col n
  unsigned short* vb = vV + (size_t)b * 256 * NPIX;
  #pragma unroll
  for (int vc2 = 0; vc2 < 2; ++vc2)
    #pragma unroll
    for (int nt = 0; nt < 2; ++nt)
      #pragma unroll
      for (int r = 0; r < 16; ++r) {
        int vc = w * 64 + vc2 * 32 + (r & 3) + 8 * (r >> 2) + 4 * hi;
        int n = n0 + nt * 32 + l31;
        vb[(size_t)vc * NPIX + n] = bfb(av[vc2][nt][r] + bv[vc]);
      }
}

// ---------------- kernel 2: fused flash attention ----------------
// S^T = K^T Q (swapped), online softmax over rows (keys), O^T = V P^T
__launch_bounds__(256, 1)
__global__ void k_attn(const unsigned short* __restrict__ qT,
                       const unsigned short* __restrict__ kT,
                       const unsigned short* __restrict__ vV,
                       unsigned short* __restrict__ oT) {
  __shared__ __align__(16) unsigned short Kl[64 * 128];   // [kp][d] swizzled
  __shared__ __align__(16) unsigned short Vl[256 * 64];   // [vc][kp] swizzled
  const int b = blockIdx.x & 7;          // XCD-affine: one batch per XCD
  const int qt = blockIdx.x >> 3;
  const int t = threadIdx.x, w = t >> 6, lane = t & 63, l31 = lane & 31, hi = lane >> 5;
  const int qp = qt * 128 + w * 32 + l31;
  const unsigned short* qTb = qT + (size_t)b * NPIX * 128;
  const unsigned short* kTb = kT + (size_t)b * NPIX * 128;
  const unsigned short* vb  = vV + (size_t)b * 256 * NPIX;
  bf16x8 qf[8];
  #pragma unroll
  for (int s = 0; s < 8; ++s)
    qf[s] = *reinterpret_cast<const bf16x8*>(qTb + (size_t)qp * 128 + s * 16 + hi * 8);
  f32x16 O[8];
  #pragma unroll
  for (int vt = 0; vt < 8; ++vt)
    #pragma unroll
    for (int i = 0; i < 16; ++i) O[vt][i] = 0.f;
  float m_run = -3.0e38f, l_run = 0.0f;

  for (int kt = 0; kt < 64; ++kt) {
    const int kp0 = kt * 64;
    // stage K tile [64][128] (swizzled dest, linear source)
    #pragma unroll
    for (int i = 0; i < 4; ++i) {
      int row = w * 16 + i * 4 + (lane >> 4);
      int c2 = (lane & 15) * 16;
      uint4v d = *reinterpret_cast<const uint4v*>(
          reinterpret_cast<const char*>(kTb) + (size_t)(kp0 + row) * 256 + c2);
      *reinterpret_cast<uint4v*>(reinterpret_cast<char*>(Kl) + row * 256 + (c2 ^ ((row & 7) << 4))) = d;
    }
    // stage V tile [256][64]
    #pragma unroll
    for (int i = 0; i < 8; ++i) {
      int vc = w * 64 + i * 8 + (lane >> 3);
      int c2 = (lane & 7) * 16;
      uint4v d = *reinterpret_cast<const uint4v*>(
          reinterpret_cast<const char*>(vb) + (size_t)vc * 8192 + kp0 * 2 + c2);
      *reinterpret_cast<uint4v*>(reinterpret_cast<char*>(Vl) + vc * 128 + (c2 ^ ((vc & 7) << 4))) = d;
    }
    __syncthreads();
    #pragma unroll
    for (int rt = 0; rt < 2; ++rt) {
      f32x16 S;
      #pragma unroll
      for (int i = 0; i < 16; ++i) S[i] = 0.f;
      #pragma unroll
      for (int s = 0; s < 8; ++s) {  // d = 128 = 8 steps
        int row = rt * 32 + l31;
        int byteoff = row * 256 + ((s * 32 + hi * 16) ^ ((row & 7) << 4));
        bf16x8 ka = *reinterpret_cast<const bf16x8*>(reinterpret_cast<const char*>(Kl) + byteoff);
        S = mfma32(ka, qf[s], S);  // S^T[kp][qp]
      }
      // column (key-wise) max: in-lane 16 + partner lane^32
      float mx = S[0];
      #pragma unroll
      for (int i = 1; i < 16; ++i) mx = fmaxf(mx, S[i]);
      mx = fmaxf(mx, __shfl_xor(mx, 32));
      if (__any(mx > m_run + 8.0f)) {  // defer-max (T13)
        float mn = fmaxf(m_run, mx);
        float al = __expf(m_run - mn);
        l_run *= al;
        #pragma unroll
        for (int vt = 0; vt < 8; ++vt)
          #pragma unroll
          for (int i = 0; i < 16; ++i) O[vt][i] *= al;
        m_run = mn;
      }
      float p[16], sum = 0.f;
      #pragma unroll
      for (int i = 0; i < 16; ++i) { p[i] = __expf(S[i] - m_run); sum += p[i]; }
      sum += __shfl_xor(sum, 32);
      l_run += sum;
      // pack P to bf16 A/B fragments: pairs + half swaps
      unsigned wd[8];
      #pragma unroll
      for (int i = 0; i < 8; ++i) wd[i] = pack2(p[2 * i], p[2 * i + 1]);
      #pragma unroll
      for (int pr = 0; pr < 4; ++pr) {
        int ia = (pr & 1) + (pr >> 1) * 4;      // 0,1,4,5
        int ib = ia + 2;                         // 2,3,6,7
        unsigned xs = (unsigned)__shfl_xor((int)wd[ia], 32);
        unsigned ys = (unsigned)__shfl_xor((int)wd[ib], 32);
        unsigned na = hi ? ys : wd[ia];
        unsigned nb = hi ? wd[ib] : xs;
        wd[ia] = na; wd[ib] = nb;
      }
      bf16x8 pf[2];
      { uint4v u; u.x = wd[0]; u.y = wd[1]; u.z = wd[2]; u.w = wd[3];
        pf[0] = __builtin_bit_cast(bf16x8, u); }
      { uint4v u; u.x = wd[4]; u.y = wd[5]; u.z = wd[6]; u.w = wd[7];
        pf[1] = __builtin_bit_cast(bf16x8, u); }
      // PV: O^T[vc][qp] += V[vc,kp] * P^T[kp,qp]
      #pragma unroll
      for (int sl = 0; sl < 2; ++sl) {
        #pragma unroll
        for (int vt = 0; vt < 8; ++vt) {
          int vc = vt * 32 + l31;
          int byteoff = vc * 128 + (((rt * 2 + sl) * 32 + hi * 16) ^ ((vc & 7) << 4));
          bf16x8 va = *reinterpret_cast<const bf16x8*>(reinterpret_cast<const char*>(Vl) + byteoff);
          O[vt] = mfma32(va, pf[sl], O[vt]);
        }
      }
    }
    __syncthreads();
  }
  float rl = 1.0f / l_run;
  unsigned short* oTb = oT + (size_t)b * NPIX * 256;  // [qp][vc]
  #pragma unroll
  for (int vt = 0; vt < 8; ++vt)
    #pragma unroll
    for (int i = 0; i < 16; i += 2) {
      int vc = vt * 32 + (i & 3) + 8 * (i >> 2) + 4 * hi;
      unsigned pk = pack2(O[vt][i] * rl, O[vt][i + 1] * rl);
      *reinterpret_cast<unsigned*>(oTb + (size_t)qp * 256 + vc) = pk;
    }
}

// ---------------- kernel 3: output projection + residual ----------------
__launch_bounds__(256, 2)
__global__ void k_out(const unsigned short* __restrict__ oT,
                      const unsigned short* __restrict__ wr,
                      const float* __restrict__ br, const float* __restrict__ gamma,
                      const float* __restrict__ x, float* __restrict__ out) {
  const int b = blockIdx.x & 7;
  const int n0 = (blockIdx.x >> 3) * 64;
  const int t = threadIdx.x, w = t >> 6, lane = t & 63, l31 = lane & 31, hi = lane >> 5;
  const unsigned short* oTb = oT + (size_t)b * NPIX * 256;
  f32x16 acc[2][2];
  #pragma unroll
  for (int a0 = 0; a0 < 2; ++a0)
    #pragma unroll
    for (int a1 = 0; a1 < 2; ++a1)
      #pragma unroll
      for (int i = 0; i < 16; ++i) acc[a0][a1][i] = 0.f;
  #pragma unroll
  for (int s = 0; s < 16; ++s) {  // K = 256 (vc)
    bf16x8 ofr[2], wfr[2];
    #pragma unroll
    for (int nt = 0; nt < 2; ++nt) {
      int n = n0 + nt * 32 + l31;
      ofr[nt] = *reinterpret_cast<const bf16x8*>(oTb + (size_t)n * 256 + s * 16 + hi * 8);
    }
    #pragma unroll
    for (int c2 = 0; c2 < 2; ++c2) {
      int c = w * 64 + c2 * 32 + l31;
      wfr[c2] = *reinterpret_cast<const bf16x8*>(wr + c * 256 + s * 16 + hi * 8);
    }
    #pragma unroll
    for (int c2 = 0; c2 < 2; ++c2)
      #pragma unroll
      for (int nt = 0; nt < 2; ++nt)
        acc[c2][nt] = mfma32(wfr[c2], ofr[nt], acc[c2][nt]);  // D[c, n]
  }
  float g = gamma[0];
  #pragma unroll
  for (int c2 = 0; c2 < 2; ++c2)
    #pragma unroll
    for (int nt = 0; nt < 2; ++nt)
      #pragma unroll
      for (int r = 0; r < 16; ++r) {
        int c = w * 64 + c2 * 32 + (r & 3) + 8 * (r >> 2) + 4 * hi;
        int n = n0 + nt * 32 + l31;
        size_t idx = (size_t)b * 256 * NPIX + (size_t)c * NPIX + n;
        out[idx] = g * (acc[c2][nt][r] + br[c]) + x[idx];
      }
}

extern "C" void kernel_launch(void* const* d_in, const int* in_sizes, int n_in,
                              void* d_out, int out_size, void* d_ws, size_t ws_size,
                              hipStream_t stream) {
  const float* x     = (const float*)d_in[0];
  const float* Wk    = (const float*)d_in[1];
  const float* bk    = (const float*)d_in[2];
  const float* Wq    = (const float*)d_in[3];
  const float* bq    = (const float*)d_in[4];
  const float* Wv    = (const float*)d_in[5];
  const float* bv    = (const float*)d_in[6];
  const float* Wr    = (const float*)d_in[7];
  const float* br    = (const float*)d_in[8];
  const float* gamma = (const float*)d_in[9];

  const size_t OFF_QT  = 0;
  const size_t OFF_KT  = 8388608;
  const size_t OFF_V   = 16777216;
  const size_t OFF_OT  = 33554432;
  const size_t OFF_WQK = 50331648;
  const size_t OFF_WV  = 50462720;
  const size_t OFF_WR  = 50593792;
  const size_t NEED    = 50724864;
  if (ws_size < NEED) return;  // cannot run without scratch

  char* ws = (char*)d_ws;
  unsigned short* qT  = (unsigned short*)(ws + OFF_QT);
  unsigned short* kT  = (unsigned short*)(ws + OFF_KT);
  unsigned short* vV  = (unsigned short*)(ws + OFF_V);
  unsigned short* oT  = (unsigned short*)(ws + OFF_OT);
  unsigned short* wqk = (unsigned short*)(ws + OFF_WQK);
  unsigned short* wvb = (unsigned short*)(ws + OFF_WV);
  unsigned short* wrb = (unsigned short*)(ws + OFF_WR);

  k_cvt<<<256, 256, 0, stream>>>(Wq, Wk, Wv, Wr, wqk, wvb, wrb);
  k_qkv<<<512, 256, 0, stream>>>(x, wqk, wvb, bq, bk, bv, qT, kT, vV);
  k_attn<<<256, 256, 0, stream>>>(qT, kT, vV, oT);
  k_out<<<512, 256, 0, stream>>>(oT, wrb, br, gamma, x, (float*)d_out);
}